// Round 9
// baseline (169.224 us; speedup 1.0000x reference)
//
#include <hip/hip_runtime.h>
#include <stdint.h>
#include <math.h>

// Problem constants
#define BB   1024
#define TT   197
#define SS   196
#define DD   64
#define MM   200704   // BB*SS   (outputs per side)
#define GG   201728   // BB*TT   (param rows per table)
#define MROWS 256     // rows per MLP block (1 per thread)
#define MBLK  788     // GG/MROWS blocks per side

// ---------------- Threefry2x32 (exact JAX rolled variant) ----------------
static __host__ __device__ inline uint32_t rotl_(uint32_t x, int r) {
  return (x << r) | (x >> (32 - r));
}

static __host__ __device__ inline void tf2x32(uint32_t k0, uint32_t k1,
                                              uint32_t& x0, uint32_t& x1) {
  uint32_t ks2 = k0 ^ k1 ^ 0x1BD11BDAu;
  x0 += k0; x1 += k1;
  x0 += x1; x1 = rotl_(x1,13); x1 ^= x0;
  x0 += x1; x1 = rotl_(x1,15); x1 ^= x0;
  x0 += x1; x1 = rotl_(x1,26); x1 ^= x0;
  x0 += x1; x1 = rotl_(x1, 6); x1 ^= x0;
  x0 += k1;  x1 += ks2 + 1u;
  x0 += x1; x1 = rotl_(x1,17); x1 ^= x0;
  x0 += x1; x1 = rotl_(x1,29); x1 ^= x0;
  x0 += x1; x1 = rotl_(x1,16); x1 ^= x0;
  x0 += x1; x1 = rotl_(x1,24); x1 ^= x0;
  x0 += ks2; x1 += k0 + 2u;
  x0 += x1; x1 = rotl_(x1,13); x1 ^= x0;
  x0 += x1; x1 = rotl_(x1,15); x1 ^= x0;
  x0 += x1; x1 = rotl_(x1,26); x1 ^= x0;
  x0 += x1; x1 = rotl_(x1, 6); x1 ^= x0;
  x0 += k0;  x1 += k1 + 3u;
  x0 += x1; x1 = rotl_(x1,17); x1 ^= x0;
  x0 += x1; x1 = rotl_(x1,29); x1 ^= x0;
  x0 += x1; x1 = rotl_(x1,16); x1 ^= x0;
  x0 += x1; x1 = rotl_(x1,24); x1 ^= x0;
  x0 += k1;  x1 += ks2 + 4u;
  x0 += x1; x1 = rotl_(x1,13); x1 ^= x0;
  x0 += x1; x1 = rotl_(x1,15); x1 ^= x0;
  x0 += x1; x1 = rotl_(x1,26); x1 ^= x0;
  x0 += x1; x1 = rotl_(x1, 6); x1 ^= x0;
  x0 += ks2; x1 += k0 + 5u;
}

// XLA ErfInv (float32 Giles polynomial), exact non-contracted rounding.
static __device__ inline float erfinv_xla(float x) {
  float w = -log1pf(-__fmul_rn(x, x));
  float p;
  if (w < 5.0f) {
    w = __fsub_rn(w, 2.5f);
    p = 2.81022636e-08f;
    p = __fadd_rn(__fmul_rn(p, w), 3.43273939e-07f);
    p = __fadd_rn(__fmul_rn(p, w), -3.5233877e-06f);
    p = __fadd_rn(__fmul_rn(p, w), -4.39150654e-06f);
    p = __fadd_rn(__fmul_rn(p, w), 0.00021858087f);
    p = __fadd_rn(__fmul_rn(p, w), -0.00125372503f);
    p = __fadd_rn(__fmul_rn(p, w), -0.00417768164f);
    p = __fadd_rn(__fmul_rn(p, w), 0.246640727f);
    p = __fadd_rn(__fmul_rn(p, w), 1.50140941f);
  } else {
    w = __fsub_rn(sqrtf(w), 3.0f);
    p = -0.000200214257f;
    p = __fadd_rn(__fmul_rn(p, w), 0.000100950558f);
    p = __fadd_rn(__fmul_rn(p, w), 0.00134934322f);
    p = __fadd_rn(__fmul_rn(p, w), -0.00367342844f);
    p = __fadd_rn(__fmul_rn(p, w), 0.00573950773f);
    p = __fadd_rn(__fmul_rn(p, w), -0.0076224613f);
    p = __fadd_rn(__fmul_rn(p, w), 0.00943887047f);
    p = __fadd_rn(__fmul_rn(p, w), 1.00167406f);
    p = __fadd_rn(__fmul_rn(p, w), 2.83297682f);
  }
  return __fmul_rn(p, x);
}

// eps[e] of jax.random.normal under jax_threefry_partitionable=True:
// per-element counter PRF, counter (hi=0, lo=e), draw = x0out ^ x1out.
static __device__ inline float jax_normal_elem(uint32_t k0, uint32_t k1, uint32_t e) {
  uint32_t c0 = 0u, c1 = e;
  tf2x32(k0, k1, c0, c1);
  uint32_t bits = c0 ^ c1;
  float f = __fsub_rn(__uint_as_float((bits >> 9) | 0x3F800000u), 1.0f); // [0,1)
  const float lo = -0.99999994f;
  float u = fmaxf(lo, __fadd_rn(__fmul_rn(f, 2.0f), lo));
  return __fmul_rn(1.41421356237309515f, erfinv_xla(u));
}

static __device__ inline float softplus_(float x) {
  return __fadd_rn(fmaxf(x, 0.0f), log1pf(expf(-fabsf(x))));
}

static __device__ inline float sigmoid_(float x) {
  if (x >= 0.0f) return 1.0f / (1.0f + expf(-x));
  float e = expf(x);
  return e / (1.0f + e);
}

// ---------------- Kernel 1: argmax, shuffle-free, phase-split blocks ----------------
// (unchanged)
__global__ __launch_bounds__(256) void argmax_kernel(
    const float* __restrict__ sim, int* __restrict__ idx_p, int* __restrict__ idx_i) {
  int bid = blockIdx.x;
  int b = bid >> 1, phase = bid & 1;
  int j = threadIdx.x;
  if (j >= SS) return;
  const float* S = sim + (size_t)b * (TT * TT);

  if (phase == 0) {
    const float* p = S + TT + 1 + j;   // S[1][1+j]
    float v0 = -INFINITY, v1 = -INFINITY, v2 = -INFINITY, v3 = -INFINITY;
    int t0 = 0, t1 = 1, t2 = 2, t3 = 3;
    for (int t = 0; t < SS; t += 4) {
      float a = p[(size_t)(t + 0) * TT];
      float c1 = p[(size_t)(t + 1) * TT];
      float c2 = p[(size_t)(t + 2) * TT];
      float c3 = p[(size_t)(t + 3) * TT];
      if (a  > v0) { v0 = a;  t0 = t; }
      if (c1 > v1) { v1 = c1; t1 = t + 1; }
      if (c2 > v2) { v2 = c2; t2 = t + 2; }
      if (c3 > v3) { v3 = c3; t3 = t + 3; }
    }
    float bv = v0; int bt = t0;
    if (v1 > bv || (v1 == bv && t1 < bt)) { bv = v1; bt = t1; }
    if (v2 > bv || (v2 == bv && t2 < bt)) { bv = v2; bt = t2; }
    if (v3 > bv || (v3 == bv && t3 < bt)) { bv = v3; bt = t3; }
    idx_i[(size_t)b * SS + j] = bt;
  } else {
    const float* q = S + (size_t)(j + 1) * TT + 1;   // S[1+j][1]
    float v[4] = {-INFINITY, -INFINITY, -INFINITY, -INFINITY};
    int   ci[4] = {0, 1, 2, 3};
    for (int c = 0; c < 192; c += 16) {
      #pragma unroll
      for (int u = 0; u < 16; ++u) {
        float x = q[c + u];
        int k = u & 3;
        if (x > v[k]) { v[k] = x; ci[k] = c + u; }
      }
    }
    #pragma unroll
    for (int u = 0; u < 4; ++u) {
      float x = q[192 + u];
      if (x > v[u]) { v[u] = x; ci[u] = 192 + u; }
    }
    float bv = v[0]; int bc = ci[0];
    #pragma unroll
    for (int k = 1; k < 4; ++k)
      if (v[k] > bv || (v[k] == bv && ci[k] < bc)) { bv = v[k]; bc = ci[k]; }
    idx_p[(size_t)b * SS + j] = bc;
  }
}

// ---------------- Kernel 2: MLP, row-per-thread, barrier-free main loop ----------------
// Thread tid owns row g0+tid: acc[64] in VGPRs; x-row streamed from global in
// 4 pipelined chunks; W1 row k read as LDS same-address broadcast (16 x b128,
// conflict-free). Layer 2 is a per-thread 64x4 dot (no cross-lane reduce).
// One barrier total (after weight staging).
__global__ __launch_bounds__(256, 2) void mlp_kernel(
    const float* __restrict__ Xp, const float* __restrict__ Xi,
    const float* __restrict__ tW1, const float* __restrict__ tb1,
    const float* __restrict__ tW2, const float* __restrict__ tb2,
    const float* __restrict__ iW1, const float* __restrict__ ib1,
    const float* __restrict__ iW2, const float* __restrict__ ib2,
    float4* __restrict__ params_t, float4* __restrict__ params_i) {
  __shared__ float  W1s[64][64];   // 16 KB, row k contiguous (256 B)
  __shared__ float4 W2s[64];       // 1 KB
  __shared__ float  b1s[64];
  __shared__ float  b2s[4];

  int tid = threadIdx.x;
  int bid = blockIdx.x;
  int side = (bid >= MBLK) ? 1 : 0;
  const float* X  = side ? Xi  : Xp;
  const float* W1 = side ? iW1 : tW1;
  const float* B1 = side ? ib1 : tb1;
  const float* W2 = side ? iW2 : tW2;
  const float* B2 = side ? ib2 : tb2;
  float4* params  = side ? params_i : params_t;
  size_t g0 = (size_t)(side ? bid - MBLK : bid) * MROWS;

  // stage weights
  {
    const float4* w4 = (const float4*)W1;
    float4* s4 = (float4*)&W1s[0][0];
    #pragma unroll
    for (int i = 0; i < 4; ++i) s4[tid + 256 * i] = w4[tid + 256 * i];
  }
  if (tid < 64) {
    W2s[tid] = ((const float4*)W2)[tid];
    b1s[tid] = B1[tid];
  }
  if (tid < 4) b2s[tid] = B2[tid];

  const float4* xr = (const float4*)(X + (g0 + (size_t)tid) * 64);

  // prefetch chunk 0 (k = 0..15) while weights stage
  float4 n0 = xr[0], n1 = xr[1], n2 = xr[2], n3 = xr[3];

  __syncthreads();   // weights + biases visible

  float acc[64];
  #pragma unroll
  for (int j = 0; j < 64; ++j) acc[j] = b1s[j];   // broadcast reads

  // 4 chunk-phases, rolled (keeps code ~10KB); inner 16-k fully unrolled so
  // all register indices are static.
  #pragma unroll 1
  for (int ph = 0; ph < 4; ++ph) {
    float4 c0 = n0, c1 = n1, c2 = n2, c3 = n3;
    if (ph < 3) {   // prefetch next chunk; lands under this phase's 1024 FMAs
      n0 = xr[4 * ph + 4]; n1 = xr[4 * ph + 5];
      n2 = xr[4 * ph + 6]; n3 = xr[4 * ph + 7];
    }
    float xs[16];
    xs[ 0] = c0.x; xs[ 1] = c0.y; xs[ 2] = c0.z; xs[ 3] = c0.w;
    xs[ 4] = c1.x; xs[ 5] = c1.y; xs[ 6] = c1.z; xs[ 7] = c1.w;
    xs[ 8] = c2.x; xs[ 9] = c2.y; xs[10] = c2.z; xs[11] = c2.w;
    xs[12] = c3.x; xs[13] = c3.y; xs[14] = c3.z; xs[15] = c3.w;

    const float4* wbase = (const float4*)&W1s[16 * ph][0];
    #pragma unroll
    for (int k = 0; k < 16; ++k) {
      float xk = xs[k];                      // static index (unrolled)
      const float4* wrow = wbase + 16 * k;   // W1s row (16*ph+k), 16 x b128 broadcast
      #pragma unroll
      for (int q = 0; q < 16; ++q) {
        float4 w = wrow[q];
        acc[4 * q + 0] = fmaf(xk, w.x, acc[4 * q + 0]);
        acc[4 * q + 1] = fmaf(xk, w.y, acc[4 * q + 1]);
        acc[4 * q + 2] = fmaf(xk, w.z, acc[4 * q + 2]);
        acc[4 * q + 3] = fmaf(xk, w.w, acc[4 * q + 3]);
      }
    }
  }

  // relu
  #pragma unroll
  for (int j = 0; j < 64; ++j) acc[j] = fmaxf(acc[j], 0.0f);

  // layer 2: per-thread 64x4 dot, j ascending (matches matmul reduction order)
  float p0 = 0.0f, p1 = 0.0f, p2 = 0.0f, p3 = 0.0f;
  #pragma unroll
  for (int j = 0; j < 64; ++j) {
    float4 w2 = W2s[j];                      // broadcast
    p0 = fmaf(acc[j], w2.x, p0);
    p1 = fmaf(acc[j], w2.y, p1);
    p2 = fmaf(acc[j], w2.z, p2);
    p3 = fmaf(acc[j], w2.w, p3);
  }

  float m0 = p0 + b2s[0];
  float m1 = p1 + b2s[1];
  float s0 = __fadd_rn(softplus_(p2 + b2s[2]), 1e-07f);
  float s1 = __fadd_rn(softplus_(p3 + b2s[3]), 1e-07f);
  params[g0 + tid] = make_float4(m0, m1, s0, s1);   // coalesced 16B/lane
}

// ---------------- Kernel 3: gather params, sample eps, log-prob diff ----------------
__global__ __launch_bounds__(256) void combine_kernel(
    const int* __restrict__ idx_p, const int* __restrict__ idx_i,
    const float4* __restrict__ params_t, const float4* __restrict__ params_i,
    float* __restrict__ out,
    uint32_t k1a, uint32_t k1b, uint32_t k2a, uint32_t k2b) {
  int id = blockIdx.x * 256 + threadIdx.x;
  int side = (id >= MM) ? 1 : 0;             // wave-uniform (MM % 256 == 0)
  int m = id - side * MM;
  int b = m / SS;
  int t = m - b * SS;

  float4 pa, pb;
  uint32_t ka, kb;
  if (!side) {
    pa = params_t[(size_t)b * TT + 1 + t];
    pb = params_i[(size_t)b * TT + idx_p[m]];
    ka = k1a; kb = k1b;
  } else {
    pa = params_i[(size_t)b * TT + 1 + t];
    pb = params_t[(size_t)b * TT + idx_i[m]];
    ka = k2a; kb = k2b;
  }

  uint32_t e0 = 2u * (uint32_t)m;
  float eps0 = jax_normal_elem(ka, kb, e0);
  float eps1 = jax_normal_elem(ka, kb, e0 + 1u);

  float z0 = __fadd_rn(pa.x, __fmul_rn(pa.z, eps0));
  float z1 = __fadd_rn(pa.y, __fmul_rn(pa.w, eps1));

  const float HLOG2PI = 0.91893853320467274f;
  float ea0 = __fsub_rn(z0, pa.x) / pa.z;
  float ea1 = __fsub_rn(z1, pa.y) / pa.w;
  float eb0 = __fsub_rn(z0, pb.x) / pb.z;
  float eb1 = __fsub_rn(z1, pb.y) / pb.w;

  float la0 = __fsub_rn(__fsub_rn(__fmul_rn(-0.5f, __fmul_rn(ea0, ea0)), logf(pa.z)), HLOG2PI);
  float la1 = __fsub_rn(__fsub_rn(__fmul_rn(-0.5f, __fmul_rn(ea1, ea1)), logf(pa.w)), HLOG2PI);
  float lb0 = __fsub_rn(__fsub_rn(__fmul_rn(-0.5f, __fmul_rn(eb0, eb0)), logf(pb.z)), HLOG2PI);
  float lb1 = __fsub_rn(__fsub_rn(__fmul_rn(-0.5f, __fmul_rn(eb1, eb1)), logf(pb.w)), HLOG2PI);
  float lpa = __fadd_rn(la0, la1);
  float lpb = __fadd_rn(lb0, lb1);

  out[id] = sigmoid_(sigmoid_(__fsub_rn(lpa, lpb)));
}

// ---------------- Launch ----------------
extern "C" void kernel_launch(void* const* d_in, const int* in_sizes, int n_in,
                              void* d_out, int out_size, void* d_ws, size_t ws_size,
                              hipStream_t stream) {
  const float* post  = (const float*)d_in[0];
  const float* image = (const float*)d_in[1];
  const float* sim   = (const float*)d_in[2];
  const float* tW1 = (const float*)d_in[3];
  const float* tb1 = (const float*)d_in[4];
  const float* tW2 = (const float*)d_in[5];
  const float* tb2 = (const float*)d_in[6];
  const float* iW1 = (const float*)d_in[7];
  const float* ib1 = (const float*)d_in[8];
  const float* iW2 = (const float*)d_in[9];
  const float* ib2 = (const float*)d_in[10];
  float* out = (float*)d_out;

  int* idx_p = (int*)d_ws;
  int* idx_i = idx_p + MM;
  float4* params_t = (float4*)(idx_i + MM);       // GG float4s
  float4* params_i = params_t + GG;

  // jax.random.split(key(42)) under threefry_partitionable:
  // child i = full 64-bit PRF output at counter (hi=0, lo=i).
  uint32_t k1a = 0, k1b = 0; tf2x32(0u, 42u, k1a, k1b);   // child 0
  uint32_t k2a = 0, k2b = 1; tf2x32(0u, 42u, k2a, k2b);   // child 1

  argmax_kernel<<<dim3(2 * BB), dim3(256), 0, stream>>>(sim, idx_p, idx_i);
  mlp_kernel<<<dim3(2 * MBLK), dim3(256), 0, stream>>>(
      post, image, tW1, tb1, tW2, tb2, iW1, ib1, iW2, ib2, params_t, params_i);
  combine_kernel<<<dim3((2 * MM) / 256), dim3(256), 0, stream>>>(
      idx_p, idx_i, params_t, params_i, out, k1a, k1b, k2a, k2b);
}

// Round 10
// 157.869 us; speedup vs baseline: 1.0719x; 1.0719x over previous
//
#include <hip/hip_runtime.h>
#include <stdint.h>
#include <math.h>

// Problem constants
#define BB   1024
#define TT   197
#define SS   196
#define DD   64
#define MM   200704   // BB*SS   (outputs per side)
#define GG   201728   // BB*TT   (param rows per table)
#define MROWS 256     // rows per MLP block
#define MBLK  788     // GG/MROWS blocks per side
#define NMLP  1576    // 2*MBLK
#define NAMX  2048    // 2*BB
#define NFUSE 3624    // NMLP + NAMX; interleaved 1:1 for bid<3152, tail argmax

// ---------------- Threefry2x32 (exact JAX rolled variant) ----------------
static __host__ __device__ inline uint32_t rotl_(uint32_t x, int r) {
  return (x << r) | (x >> (32 - r));
}

static __host__ __device__ inline void tf2x32(uint32_t k0, uint32_t k1,
                                              uint32_t& x0, uint32_t& x1) {
  uint32_t ks2 = k0 ^ k1 ^ 0x1BD11BDAu;
  x0 += k0; x1 += k1;
  x0 += x1; x1 = rotl_(x1,13); x1 ^= x0;
  x0 += x1; x1 = rotl_(x1,15); x1 ^= x0;
  x0 += x1; x1 = rotl_(x1,26); x1 ^= x0;
  x0 += x1; x1 = rotl_(x1, 6); x1 ^= x0;
  x0 += k1;  x1 += ks2 + 1u;
  x0 += x1; x1 = rotl_(x1,17); x1 ^= x0;
  x0 += x1; x1 = rotl_(x1,29); x1 ^= x0;
  x0 += x1; x1 = rotl_(x1,16); x1 ^= x0;
  x0 += x1; x1 = rotl_(x1,24); x1 ^= x0;
  x0 += ks2; x1 += k0 + 2u;
  x0 += x1; x1 = rotl_(x1,13); x1 ^= x0;
  x0 += x1; x1 = rotl_(x1,15); x1 ^= x0;
  x0 += x1; x1 = rotl_(x1,26); x1 ^= x0;
  x0 += x1; x1 = rotl_(x1, 6); x1 ^= x0;
  x0 += k0;  x1 += k1 + 3u;
  x0 += x1; x1 = rotl_(x1,17); x1 ^= x0;
  x0 += x1; x1 = rotl_(x1,29); x1 ^= x0;
  x0 += x1; x1 = rotl_(x1,16); x1 ^= x0;
  x0 += x1; x1 = rotl_(x1,24); x1 ^= x0;
  x0 += k1;  x1 += ks2 + 4u;
  x0 += x1; x1 = rotl_(x1,13); x1 ^= x0;
  x0 += x1; x1 = rotl_(x1,15); x1 ^= x0;
  x0 += x1; x1 = rotl_(x1,26); x1 ^= x0;
  x0 += x1; x1 = rotl_(x1, 6); x1 ^= x0;
  x0 += ks2; x1 += k0 + 5u;
}

// XLA ErfInv (float32 Giles polynomial), exact non-contracted rounding.
static __device__ inline float erfinv_xla(float x) {
  float w = -log1pf(-__fmul_rn(x, x));
  float p;
  if (w < 5.0f) {
    w = __fsub_rn(w, 2.5f);
    p = 2.81022636e-08f;
    p = __fadd_rn(__fmul_rn(p, w), 3.43273939e-07f);
    p = __fadd_rn(__fmul_rn(p, w), -3.5233877e-06f);
    p = __fadd_rn(__fmul_rn(p, w), -4.39150654e-06f);
    p = __fadd_rn(__fmul_rn(p, w), 0.00021858087f);
    p = __fadd_rn(__fmul_rn(p, w), -0.00125372503f);
    p = __fadd_rn(__fmul_rn(p, w), -0.00417768164f);
    p = __fadd_rn(__fmul_rn(p, w), 0.246640727f);
    p = __fadd_rn(__fmul_rn(p, w), 1.50140941f);
  } else {
    w = __fsub_rn(sqrtf(w), 3.0f);
    p = -0.000200214257f;
    p = __fadd_rn(__fmul_rn(p, w), 0.000100950558f);
    p = __fadd_rn(__fmul_rn(p, w), 0.00134934322f);
    p = __fadd_rn(__fmul_rn(p, w), -0.00367342844f);
    p = __fadd_rn(__fmul_rn(p, w), 0.00573950773f);
    p = __fadd_rn(__fmul_rn(p, w), -0.0076224613f);
    p = __fadd_rn(__fmul_rn(p, w), 0.00943887047f);
    p = __fadd_rn(__fmul_rn(p, w), 1.00167406f);
    p = __fadd_rn(__fmul_rn(p, w), 2.83297682f);
  }
  return __fmul_rn(p, x);
}

// eps[e] of jax.random.normal under jax_threefry_partitionable=True:
// per-element counter PRF, counter (hi=0, lo=e), draw = x0out ^ x1out.
static __device__ inline float jax_normal_elem(uint32_t k0, uint32_t k1, uint32_t e) {
  uint32_t c0 = 0u, c1 = e;
  tf2x32(k0, k1, c0, c1);
  uint32_t bits = c0 ^ c1;
  float f = __fsub_rn(__uint_as_float((bits >> 9) | 0x3F800000u), 1.0f); // [0,1)
  const float lo = -0.99999994f;
  float u = fmaxf(lo, __fadd_rn(__fmul_rn(f, 2.0f), lo));
  return __fmul_rn(1.41421356237309515f, erfinv_xla(u));
}

static __device__ inline float softplus_(float x) {
  return __fadd_rn(fmaxf(x, 0.0f), log1pf(expf(-fabsf(x))));
}

static __device__ inline float sigmoid_(float x) {
  if (x >= 0.0f) return 1.0f / (1.0f + expf(-x));
  float e = expf(x);
  return e / (1.0f + e);
}

// ---------------- Fused producer: argmax + MLP, role-interleaved ----------------
// bid < 3152: odd -> MLP block (mid = bid>>1), even -> argmax block (aid = bid>>1).
// bid >= 3152: argmax tail (aid = 1576 + bid - 3152).
// argmax body == R5 kernel (shuffle-free, no LDS); MLP body == R8 kernel.
__global__ __launch_bounds__(256) void fused_kernel(
    const float* __restrict__ sim,
    const float* __restrict__ Xp, const float* __restrict__ Xi,
    const float* __restrict__ tW1, const float* __restrict__ tb1,
    const float* __restrict__ tW2, const float* __restrict__ tb2,
    const float* __restrict__ iW1, const float* __restrict__ ib1,
    const float* __restrict__ iW2, const float* __restrict__ ib2,
    int* __restrict__ idx_p, int* __restrict__ idx_i,
    float4* __restrict__ params_t, float4* __restrict__ params_i) {
  __shared__ float XT[16][MROWS];   // 16 KB (MLP role only)
  __shared__ float W1s[64][64];     // 16 KB
  __shared__ float4 W2s[64];
  __shared__ float b1s[64];
  __shared__ float b2s[4];

  int bid = blockIdx.x;
  int tid = threadIdx.x;

  bool is_mlp = (bid < 3152) && (bid & 1);
  if (!is_mlp) {
    // ================= argmax role =================
    int aid = (bid < 3152) ? (bid >> 1) : (1576 + (bid - 3152));
    int b = aid >> 1, phase = aid & 1;
    int j = tid;
    if (j >= SS) return;
    const float* S = sim + (size_t)b * (TT * TT);

    if (phase == 0) {
      // column argmax: thread j scans down column j
      const float* p = S + TT + 1 + j;   // S[1][1+j]
      float v0 = -INFINITY, v1 = -INFINITY, v2 = -INFINITY, v3 = -INFINITY;
      int t0 = 0, t1 = 1, t2 = 2, t3 = 3;
      for (int t = 0; t < SS; t += 4) {
        float a  = p[(size_t)(t + 0) * TT];
        float c1 = p[(size_t)(t + 1) * TT];
        float c2 = p[(size_t)(t + 2) * TT];
        float c3 = p[(size_t)(t + 3) * TT];
        if (a  > v0) { v0 = a;  t0 = t; }
        if (c1 > v1) { v1 = c1; t1 = t + 1; }
        if (c2 > v2) { v2 = c2; t2 = t + 2; }
        if (c3 > v3) { v3 = c3; t3 = t + 3; }
      }
      float bv = v0; int bt = t0;
      if (v1 > bv || (v1 == bv && t1 < bt)) { bv = v1; bt = t1; }
      if (v2 > bv || (v2 == bv && t2 < bt)) { bv = v2; bt = t2; }
      if (v3 > bv || (v3 == bv && t3 < bt)) { bv = v3; bt = t3; }
      idx_i[(size_t)b * SS + j] = bt;
    } else {
      // row argmax: thread j scans row j in 16-wide chunks
      const float* q = S + (size_t)(j + 1) * TT + 1;   // S[1+j][1]
      float v[4] = {-INFINITY, -INFINITY, -INFINITY, -INFINITY};
      int   ci[4] = {0, 1, 2, 3};
      for (int c = 0; c < 192; c += 16) {
        #pragma unroll
        for (int u = 0; u < 16; ++u) {
          float x = q[c + u];
          int k = u & 3;
          if (x > v[k]) { v[k] = x; ci[k] = c + u; }
        }
      }
      #pragma unroll
      for (int u = 0; u < 4; ++u) {
        float x = q[192 + u];
        if (x > v[u]) { v[u] = x; ci[u] = 192 + u; }
      }
      float bv = v[0]; int bc = ci[0];
      #pragma unroll
      for (int k = 1; k < 4; ++k)
        if (v[k] > bv || (v[k] == bv && ci[k] < bc)) { bv = v[k]; bc = ci[k]; }
      idx_p[(size_t)b * SS + j] = bc;
    }
    return;
  }

  // ================= MLP role (== R8 body) =================
  int mid = bid >> 1;                  // 0..1575
  int side = (mid >= MBLK) ? 1 : 0;
  const float* X  = side ? Xi  : Xp;
  const float* W1 = side ? iW1 : tW1;
  const float* B1 = side ? ib1 : tb1;
  const float* W2 = side ? iW2 : tW2;
  const float* B2 = side ? ib2 : tb2;
  float4* params  = side ? params_i : params_t;
  size_t g0 = (size_t)(side ? mid - MBLK : mid) * MROWS;

  // stage weights
  {
    const float4* w4 = (const float4*)W1;
    float4* s4 = (float4*)&W1s[0][0];
    #pragma unroll
    for (int i = 0; i < 4; ++i) s4[tid + 256 * i] = w4[tid + 256 * i];
  }
  if (tid < 64) {
    W2s[tid] = ((const float4*)W2)[tid];
    b1s[tid] = B1[tid];
  }
  if (tid < 4) b2s[tid] = B2[tid];

  const float4* xrow4 = (const float4*)(X + (g0 + (size_t)tid) * 64);
  int tr = tid >> 3, tc = tid & 7;
  int r0 = tr * 8, c0 = tc * 8;

  float acc[8][8];

  // prefetch phase 0 (k = 0..15)
  float4 pre0 = xrow4[0], pre1 = xrow4[1], pre2 = xrow4[2], pre3 = xrow4[3];

  #pragma unroll
  for (int ph = 0; ph < 4; ++ph) {
    {
      float4 v;
      v = pre0; XT[ 0][tid] = v.x; XT[ 1][tid] = v.y; XT[ 2][tid] = v.z; XT[ 3][tid] = v.w;
      v = pre1; XT[ 4][tid] = v.x; XT[ 5][tid] = v.y; XT[ 6][tid] = v.z; XT[ 7][tid] = v.w;
      v = pre2; XT[ 8][tid] = v.x; XT[ 9][tid] = v.y; XT[10][tid] = v.z; XT[11][tid] = v.w;
      v = pre3; XT[12][tid] = v.x; XT[13][tid] = v.y; XT[14][tid] = v.z; XT[15][tid] = v.w;
    }
    if (ph < 3) {
      pre0 = xrow4[4 * (ph + 1) + 0];
      pre1 = xrow4[4 * (ph + 1) + 1];
      pre2 = xrow4[4 * (ph + 1) + 2];
      pre3 = xrow4[4 * (ph + 1) + 3];
    }
    __syncthreads();

    if (ph == 0) {
      #pragma unroll
      for (int i = 0; i < 8; ++i)
        #pragma unroll
        for (int j = 0; j < 8; ++j) acc[i][j] = b1s[c0 + j];
    }

    #pragma unroll
    for (int k = 0; k < 16; ++k) {
      float4 xa = *(const float4*)&XT[k][r0];
      float4 xb = *(const float4*)&XT[k][r0 + 4];
      float4 wa = *(const float4*)&W1s[16 * ph + k][c0];
      float4 wb = *(const float4*)&W1s[16 * ph + k][c0 + 4];
      float xr[8] = {xa.x, xa.y, xa.z, xa.w, xb.x, xb.y, xb.z, xb.w};
      float wc[8] = {wa.x, wa.y, wa.z, wa.w, wb.x, wb.y, wb.z, wb.w};
      #pragma unroll
      for (int i = 0; i < 8; ++i)
        #pragma unroll
        for (int j = 0; j < 8; ++j)
          acc[i][j] = fmaf(xr[i], wc[j], acc[i][j]);
    }
    __syncthreads();
  }

  // relu
  #pragma unroll
  for (int i = 0; i < 8; ++i)
    #pragma unroll
    for (int j = 0; j < 8; ++j) acc[i][j] = fmaxf(acc[i][j], 0.0f);

  // layer 2: partials over this thread's 8 j's, reduce across 8 tc lanes
  float p[8][4];
  #pragma unroll
  for (int i = 0; i < 8; ++i)
    #pragma unroll
    for (int c = 0; c < 4; ++c) p[i][c] = 0.0f;
  #pragma unroll
  for (int j = 0; j < 8; ++j) {
    float4 w2 = W2s[c0 + j];
    #pragma unroll
    for (int i = 0; i < 8; ++i) {
      p[i][0] = fmaf(acc[i][j], w2.x, p[i][0]);
      p[i][1] = fmaf(acc[i][j], w2.y, p[i][1]);
      p[i][2] = fmaf(acc[i][j], w2.z, p[i][2]);
      p[i][3] = fmaf(acc[i][j], w2.w, p[i][3]);
    }
  }
  #pragma unroll
  for (int off = 1; off < 8; off <<= 1)
    #pragma unroll
    for (int i = 0; i < 8; ++i)
      #pragma unroll
      for (int c = 0; c < 4; ++c)
        p[i][c] += __shfl_xor(p[i][c], off);

  if (tc == 0) {
    #pragma unroll
    for (int i = 0; i < 8; ++i) {
      float m0 = p[i][0] + b2s[0];
      float m1 = p[i][1] + b2s[1];
      float s0 = __fadd_rn(softplus_(p[i][2] + b2s[2]), 1e-07f);
      float s1 = __fadd_rn(softplus_(p[i][3] + b2s[3]), 1e-07f);
      params[g0 + r0 + i] = make_float4(m0, m1, s0, s1);
    }
  }
}

// ---------------- Kernel 2: gather params, sample eps, log-prob diff ----------------
__global__ __launch_bounds__(256) void combine_kernel(
    const int* __restrict__ idx_p, const int* __restrict__ idx_i,
    const float4* __restrict__ params_t, const float4* __restrict__ params_i,
    float* __restrict__ out,
    uint32_t k1a, uint32_t k1b, uint32_t k2a, uint32_t k2b) {
  int id = blockIdx.x * 256 + threadIdx.x;
  int side = (id >= MM) ? 1 : 0;             // wave-uniform (MM % 256 == 0)
  int m = id - side * MM;
  int b = m / SS;
  int t = m - b * SS;

  float4 pa, pb;
  uint32_t ka, kb;
  if (!side) {
    pa = params_t[(size_t)b * TT + 1 + t];
    pb = params_i[(size_t)b * TT + idx_p[m]];
    ka = k1a; kb = k1b;
  } else {
    pa = params_i[(size_t)b * TT + 1 + t];
    pb = params_t[(size_t)b * TT + idx_i[m]];
    ka = k2a; kb = k2b;
  }

  uint32_t e0 = 2u * (uint32_t)m;
  float eps0 = jax_normal_elem(ka, kb, e0);
  float eps1 = jax_normal_elem(ka, kb, e0 + 1u);

  float z0 = __fadd_rn(pa.x, __fmul_rn(pa.z, eps0));
  float z1 = __fadd_rn(pa.y, __fmul_rn(pa.w, eps1));

  const float HLOG2PI = 0.91893853320467274f;
  float ea0 = __fsub_rn(z0, pa.x) / pa.z;
  float ea1 = __fsub_rn(z1, pa.y) / pa.w;
  float eb0 = __fsub_rn(z0, pb.x) / pb.z;
  float eb1 = __fsub_rn(z1, pb.y) / pb.w;

  float la0 = __fsub_rn(__fsub_rn(__fmul_rn(-0.5f, __fmul_rn(ea0, ea0)), logf(pa.z)), HLOG2PI);
  float la1 = __fsub_rn(__fsub_rn(__fmul_rn(-0.5f, __fmul_rn(ea1, ea1)), logf(pa.w)), HLOG2PI);
  float lb0 = __fsub_rn(__fsub_rn(__fmul_rn(-0.5f, __fmul_rn(eb0, eb0)), logf(pb.z)), HLOG2PI);
  float lb1 = __fsub_rn(__fsub_rn(__fmul_rn(-0.5f, __fmul_rn(eb1, eb1)), logf(pb.w)), HLOG2PI);
  float lpa = __fadd_rn(la0, la1);
  float lpb = __fadd_rn(lb0, lb1);

  out[id] = sigmoid_(sigmoid_(__fsub_rn(lpa, lpb)));
}

// ---------------- Launch ----------------
extern "C" void kernel_launch(void* const* d_in, const int* in_sizes, int n_in,
                              void* d_out, int out_size, void* d_ws, size_t ws_size,
                              hipStream_t stream) {
  const float* post  = (const float*)d_in[0];
  const float* image = (const float*)d_in[1];
  const float* sim   = (const float*)d_in[2];
  const float* tW1 = (const float*)d_in[3];
  const float* tb1 = (const float*)d_in[4];
  const float* tW2 = (const float*)d_in[5];
  const float* tb2 = (const float*)d_in[6];
  const float* iW1 = (const float*)d_in[7];
  const float* ib1 = (const float*)d_in[8];
  const float* iW2 = (const float*)d_in[9];
  const float* ib2 = (const float*)d_in[10];
  float* out = (float*)d_out;

  int* idx_p = (int*)d_ws;
  int* idx_i = idx_p + MM;
  float4* params_t = (float4*)(idx_i + MM);       // GG float4s
  float4* params_i = params_t + GG;

  // jax.random.split(key(42)) under threefry_partitionable:
  // child i = full 64-bit PRF output at counter (hi=0, lo=i).
  uint32_t k1a = 0, k1b = 0; tf2x32(0u, 42u, k1a, k1b);   // child 0
  uint32_t k2a = 0, k2b = 1; tf2x32(0u, 42u, k2a, k2b);   // child 1

  fused_kernel<<<dim3(NFUSE), dim3(256), 0, stream>>>(
      sim, post, image, tW1, tb1, tW2, tb2, iW1, ib1, iW2, ib2,
      idx_p, idx_i, params_t, params_i);
  combine_kernel<<<dim3((2 * MM) / 256), dim3(256), 0, stream>>>(
      idx_p, idx_i, params_t, params_i, out, k1a, k1b, k2a, k2b);
}

// Round 12
// 146.594 us; speedup vs baseline: 1.1544x; 1.0769x over previous
//
#include <hip/hip_runtime.h>
#include <stdint.h>
#include <math.h>

// Problem constants
#define BB   1024
#define TT   197
#define SS   196
#define DD   64
#define MM   200704   // BB*SS   (outputs per side)
#define GG   201728   // BB*TT   (param rows per table)
#define MROWS 256     // rows per MLP block
#define MBLK  788     // GG/MROWS blocks per side

// ---------------- Threefry2x32 (exact JAX rolled variant) ----------------
static __host__ __device__ inline uint32_t rotl_(uint32_t x, int r) {
  return (x << r) | (x >> (32 - r));
}

static __host__ __device__ inline void tf2x32(uint32_t k0, uint32_t k1,
                                              uint32_t& x0, uint32_t& x1) {
  uint32_t ks2 = k0 ^ k1 ^ 0x1BD11BDAu;
  x0 += k0; x1 += k1;
  x0 += x1; x1 = rotl_(x1,13); x1 ^= x0;
  x0 += x1; x1 = rotl_(x1,15); x1 ^= x0;
  x0 += x1; x1 = rotl_(x1,26); x1 ^= x0;
  x0 += x1; x1 = rotl_(x1, 6); x1 ^= x0;
  x0 += k1;  x1 += ks2 + 1u;
  x0 += x1; x1 = rotl_(x1,17); x1 ^= x0;
  x0 += x1; x1 = rotl_(x1,29); x1 ^= x0;
  x0 += x1; x1 = rotl_(x1,16); x1 ^= x0;
  x0 += x1; x1 = rotl_(x1,24); x1 ^= x0;
  x0 += ks2; x1 += k0 + 2u;
  x0 += x1; x1 = rotl_(x1,13); x1 ^= x0;
  x0 += x1; x1 = rotl_(x1,15); x1 ^= x0;
  x0 += x1; x1 = rotl_(x1,26); x1 ^= x0;
  x0 += x1; x1 = rotl_(x1, 6); x1 ^= x0;
  x0 += k0;  x1 += k1 + 3u;
  x0 += x1; x1 = rotl_(x1,17); x1 ^= x0;
  x0 += x1; x1 = rotl_(x1,29); x1 ^= x0;
  x0 += x1; x1 = rotl_(x1,16); x1 ^= x0;
  x0 += x1; x1 = rotl_(x1,24); x1 ^= x0;
  x0 += k1;  x1 += ks2 + 4u;
  x0 += x1; x1 = rotl_(x1,13); x1 ^= x0;
  x0 += x1; x1 = rotl_(x1,15); x1 ^= x0;
  x0 += x1; x1 = rotl_(x1,26); x1 ^= x0;
  x0 += x1; x1 = rotl_(x1, 6); x1 ^= x0;
  x0 += ks2; x1 += k0 + 5u;
}

// XLA ErfInv (float32 Giles polynomial), exact non-contracted rounding.
static __device__ inline float erfinv_xla(float x) {
  float w = -log1pf(-__fmul_rn(x, x));
  float p;
  if (w < 5.0f) {
    w = __fsub_rn(w, 2.5f);
    p = 2.81022636e-08f;
    p = __fadd_rn(__fmul_rn(p, w), 3.43273939e-07f);
    p = __fadd_rn(__fmul_rn(p, w), -3.5233877e-06f);
    p = __fadd_rn(__fmul_rn(p, w), -4.39150654e-06f);
    p = __fadd_rn(__fmul_rn(p, w), 0.00021858087f);
    p = __fadd_rn(__fmul_rn(p, w), -0.00125372503f);
    p = __fadd_rn(__fmul_rn(p, w), -0.00417768164f);
    p = __fadd_rn(__fmul_rn(p, w), 0.246640727f);
    p = __fadd_rn(__fmul_rn(p, w), 1.50140941f);
  } else {
    w = __fsub_rn(sqrtf(w), 3.0f);
    p = -0.000200214257f;
    p = __fadd_rn(__fmul_rn(p, w), 0.000100950558f);
    p = __fadd_rn(__fmul_rn(p, w), 0.00134934322f);
    p = __fadd_rn(__fmul_rn(p, w), -0.00367342844f);
    p = __fadd_rn(__fmul_rn(p, w), 0.00573950773f);
    p = __fadd_rn(__fmul_rn(p, w), -0.0076224613f);
    p = __fadd_rn(__fmul_rn(p, w), 0.00943887047f);
    p = __fadd_rn(__fmul_rn(p, w), 1.00167406f);
    p = __fadd_rn(__fmul_rn(p, w), 2.83297682f);
  }
  return __fmul_rn(p, x);
}

// eps[e] of jax.random.normal under jax_threefry_partitionable=True:
// per-element counter PRF, counter (hi=0, lo=e), draw = x0out ^ x1out.
static __device__ inline float jax_normal_elem(uint32_t k0, uint32_t k1, uint32_t e) {
  uint32_t c0 = 0u, c1 = e;
  tf2x32(k0, k1, c0, c1);
  uint32_t bits = c0 ^ c1;
  float f = __fsub_rn(__uint_as_float((bits >> 9) | 0x3F800000u), 1.0f); // [0,1)
  const float lo = -0.99999994f;
  float u = fmaxf(lo, __fadd_rn(__fmul_rn(f, 2.0f), lo));
  return __fmul_rn(1.41421356237309515f, erfinv_xla(u));
}

static __device__ inline float softplus_(float x) {
  return __fadd_rn(fmaxf(x, 0.0f), log1pf(expf(-fabsf(x))));
}

static __device__ inline float sigmoid_(float x) {
  if (x >= 0.0f) return 1.0f / (1.0f + expf(-x));
  float e = expf(x);
  return e / (1.0f + e);
}

// ---------------- Kernel 1: argmax, shuffle-free, phase-split blocks ----------------
// (unchanged since R5)
__global__ __launch_bounds__(256) void argmax_kernel(
    const float* __restrict__ sim, int* __restrict__ idx_p, int* __restrict__ idx_i) {
  int bid = blockIdx.x;
  int b = bid >> 1, phase = bid & 1;
  int j = threadIdx.x;
  if (j >= SS) return;
  const float* S = sim + (size_t)b * (TT * TT);

  if (phase == 0) {
    const float* p = S + TT + 1 + j;   // S[1][1+j]
    float v0 = -INFINITY, v1 = -INFINITY, v2 = -INFINITY, v3 = -INFINITY;
    int t0 = 0, t1 = 1, t2 = 2, t3 = 3;
    for (int t = 0; t < SS; t += 4) {
      float a  = p[(size_t)(t + 0) * TT];
      float c1 = p[(size_t)(t + 1) * TT];
      float c2 = p[(size_t)(t + 2) * TT];
      float c3 = p[(size_t)(t + 3) * TT];
      if (a  > v0) { v0 = a;  t0 = t; }
      if (c1 > v1) { v1 = c1; t1 = t + 1; }
      if (c2 > v2) { v2 = c2; t2 = t + 2; }
      if (c3 > v3) { v3 = c3; t3 = t + 3; }
    }
    float bv = v0; int bt = t0;
    if (v1 > bv || (v1 == bv && t1 < bt)) { bv = v1; bt = t1; }
    if (v2 > bv || (v2 == bv && t2 < bt)) { bv = v2; bt = t2; }
    if (v3 > bv || (v3 == bv && t3 < bt)) { bv = v3; bt = t3; }
    idx_i[(size_t)b * SS + j] = bt;
  } else {
    const float* q = S + (size_t)(j + 1) * TT + 1;   // S[1+j][1]
    float v[4] = {-INFINITY, -INFINITY, -INFINITY, -INFINITY};
    int   ci[4] = {0, 1, 2, 3};
    for (int c = 0; c < 192; c += 16) {
      #pragma unroll
      for (int u = 0; u < 16; ++u) {
        float x = q[c + u];
        int k = u & 3;
        if (x > v[k]) { v[k] = x; ci[k] = c + u; }
      }
    }
    #pragma unroll
    for (int u = 0; u < 4; ++u) {
      float x = q[192 + u];
      if (x > v[u]) { v[u] = x; ci[u] = 192 + u; }
    }
    float bv = v[0]; int bc = ci[0];
    #pragma unroll
    for (int k = 1; k < 4; ++k)
      if (v[k] > bv || (v[k] == bv && ci[k] < bc)) { bv = v[k]; bc = ci[k]; }
    idx_p[(size_t)b * SS + j] = bc;
  }
}

// ---------------- Kernel 2: MLP, 8x8 tile, 4x16-k phases, ROLLED ph loop ----------------
// Identical math/order to R7, but the phase loop is NOT unrolled: loop body
// ~8.5 KB (1024 FMA + 64 ds_read_b128) fits the 32 KB I$. R6-R8's ~35 KB of
// straight-line code was instruction-fetch-bound (R9's 10 KB kernel ran at its
// DS floor; the tiled 35 KB kernels sat at 91 us regardless of occupancy).
__global__ __launch_bounds__(256) void mlp_kernel(
    const float* __restrict__ Xp, const float* __restrict__ Xi,
    const float* __restrict__ tW1, const float* __restrict__ tb1,
    const float* __restrict__ tW2, const float* __restrict__ tb2,
    const float* __restrict__ iW1, const float* __restrict__ ib1,
    const float* __restrict__ iW2, const float* __restrict__ ib2,
    float4* __restrict__ params_t, float4* __restrict__ params_i) {
  __shared__ float XT[16][MROWS];   // transposed x, one 16-k phase (16 KB)
  __shared__ float W1s[64][64];     // 16 KB
  __shared__ float4 W2s[64];
  __shared__ float b1s[64];
  __shared__ float b2s[4];

  int tid = threadIdx.x;
  int bid = blockIdx.x;
  int side = (bid >= MBLK) ? 1 : 0;
  const float* X  = side ? Xi  : Xp;
  const float* W1 = side ? iW1 : tW1;
  const float* B1 = side ? ib1 : tb1;
  const float* W2 = side ? iW2 : tW2;
  const float* B2 = side ? ib2 : tb2;
  float4* params  = side ? params_i : params_t;
  size_t g0 = (size_t)(side ? bid - MBLK : bid) * MROWS;

  // stage weights
  {
    const float4* w4 = (const float4*)W1;
    float4* s4 = (float4*)&W1s[0][0];
    #pragma unroll
    for (int i = 0; i < 4; ++i) s4[tid + 256 * i] = w4[tid + 256 * i];
  }
  if (tid < 64) {
    W2s[tid] = ((const float4*)W2)[tid];
    b1s[tid] = B1[tid];
  }
  if (tid < 4) b2s[tid] = B2[tid];

  const float4* xrow4 = (const float4*)(X + (g0 + (size_t)tid) * 64);
  int tr = tid >> 3, tc = tid & 7;
  int r0 = tr * 8, c0 = tc * 8;

  float acc[8][8];

  // prefetch phase 0 (k = 0..15)
  float4 pre0 = xrow4[0], pre1 = xrow4[1], pre2 = xrow4[2], pre3 = xrow4[3];

  #pragma unroll 1
  for (int ph = 0; ph < 4; ++ph) {
    // write current phase to XT
    {
      float4 v;
      v = pre0; XT[ 0][tid] = v.x; XT[ 1][tid] = v.y; XT[ 2][tid] = v.z; XT[ 3][tid] = v.w;
      v = pre1; XT[ 4][tid] = v.x; XT[ 5][tid] = v.y; XT[ 6][tid] = v.z; XT[ 7][tid] = v.w;
      v = pre2; XT[ 8][tid] = v.x; XT[ 9][tid] = v.y; XT[10][tid] = v.z; XT[11][tid] = v.w;
      v = pre3; XT[12][tid] = v.x; XT[13][tid] = v.y; XT[14][tid] = v.z; XT[15][tid] = v.w;
    }
    // issue prefetch of next phase (lands during compute)
    if (ph < 3) {
      pre0 = xrow4[4 * (ph + 1) + 0];
      pre1 = xrow4[4 * (ph + 1) + 1];
      pre2 = xrow4[4 * (ph + 1) + 2];
      pre3 = xrow4[4 * (ph + 1) + 3];
    }
    __syncthreads();

    if (ph == 0) {
      // initialize acc from staged b1s (safe after barrier); uniform branch
      #pragma unroll
      for (int i = 0; i < 8; ++i)
        #pragma unroll
        for (int j = 0; j < 8; ++j) acc[i][j] = b1s[c0 + j];
    }

    const float* w1base = &W1s[16 * ph][0];
    #pragma unroll
    for (int k = 0; k < 16; ++k) {
      float4 xa = *(const float4*)&XT[k][r0];
      float4 xb = *(const float4*)&XT[k][r0 + 4];
      float4 wa = *(const float4*)(w1base + 64 * k + c0);
      float4 wb = *(const float4*)(w1base + 64 * k + c0 + 4);
      float xr[8] = {xa.x, xa.y, xa.z, xa.w, xb.x, xb.y, xb.z, xb.w};
      float wc[8] = {wa.x, wa.y, wa.z, wa.w, wb.x, wb.y, wb.z, wb.w};
      #pragma unroll
      for (int i = 0; i < 8; ++i)
        #pragma unroll
        for (int j = 0; j < 8; ++j)
          acc[i][j] = fmaf(xr[i], wc[j], acc[i][j]);
    }
    __syncthreads();   // XT consumed; safe to overwrite next phase
  }

  // relu
  #pragma unroll
  for (int i = 0; i < 8; ++i)
    #pragma unroll
    for (int j = 0; j < 8; ++j) acc[i][j] = fmaxf(acc[i][j], 0.0f);

  // layer 2: partials over this thread's 8 j's, reduce across 8 tc lanes
  float p[8][4];
  #pragma unroll
  for (int i = 0; i < 8; ++i)
    #pragma unroll
    for (int c = 0; c < 4; ++c) p[i][c] = 0.0f;
  #pragma unroll
  for (int j = 0; j < 8; ++j) {
    float4 w2 = W2s[c0 + j];
    #pragma unroll
    for (int i = 0; i < 8; ++i) {
      p[i][0] = fmaf(acc[i][j], w2.x, p[i][0]);
      p[i][1] = fmaf(acc[i][j], w2.y, p[i][1]);
      p[i][2] = fmaf(acc[i][j], w2.z, p[i][2]);
      p[i][3] = fmaf(acc[i][j], w2.w, p[i][3]);
    }
  }
  #pragma unroll
  for (int off = 1; off < 8; off <<= 1)
    #pragma unroll
    for (int i = 0; i < 8; ++i)
      #pragma unroll
      for (int c = 0; c < 4; ++c)
        p[i][c] += __shfl_xor(p[i][c], off);

  if (tc == 0) {
    #pragma unroll
    for (int i = 0; i < 8; ++i) {
      float m0 = p[i][0] + b2s[0];
      float m1 = p[i][1] + b2s[1];
      float s0 = __fadd_rn(softplus_(p[i][2] + b2s[2]), 1e-07f);
      float s1 = __fadd_rn(softplus_(p[i][3] + b2s[3]), 1e-07f);
      params[g0 + r0 + i] = make_float4(m0, m1, s0, s1);
    }
  }
}

// ---------------- Kernel 3: gather params, sample eps, log-prob diff ----------------
__global__ __launch_bounds__(256) void combine_kernel(
    const int* __restrict__ idx_p, const int* __restrict__ idx_i,
    const float4* __restrict__ params_t, const float4* __restrict__ params_i,
    float* __restrict__ out,
    uint32_t k1a, uint32_t k1b, uint32_t k2a, uint32_t k2b) {
  int id = blockIdx.x * 256 + threadIdx.x;
  int side = (id >= MM) ? 1 : 0;             // wave-uniform (MM % 256 == 0)
  int m = id - side * MM;
  int b = m / SS;
  int t = m - b * SS;

  float4 pa, pb;
  uint32_t ka, kb;
  if (!side) {
    pa = params_t[(size_t)b * TT + 1 + t];
    pb = params_i[(size_t)b * TT + idx_p[m]];
    ka = k1a; kb = k1b;
  } else {
    pa = params_i[(size_t)b * TT + 1 + t];
    pb = params_t[(size_t)b * TT + idx_i[m]];
    ka = k2a; kb = k2b;
  }

  uint32_t e0 = 2u * (uint32_t)m;
  float eps0 = jax_normal_elem(ka, kb, e0);
  float eps1 = jax_normal_elem(ka, kb, e0 + 1u);

  float z0 = __fadd_rn(pa.x, __fmul_rn(pa.z, eps0));
  float z1 = __fadd_rn(pa.y, __fmul_rn(pa.w, eps1));

  const float HLOG2PI = 0.91893853320467274f;
  float ea0 = __fsub_rn(z0, pa.x) / pa.z;
  float ea1 = __fsub_rn(z1, pa.y) / pa.w;
  float eb0 = __fsub_rn(z0, pb.x) / pb.z;
  float eb1 = __fsub_rn(z1, pb.y) / pb.w;

  float la0 = __fsub_rn(__fsub_rn(__fmul_rn(-0.5f, __fmul_rn(ea0, ea0)), logf(pa.z)), HLOG2PI);
  float la1 = __fsub_rn(__fsub_rn(__fmul_rn(-0.5f, __fmul_rn(ea1, ea1)), logf(pa.w)), HLOG2PI);
  float lb0 = __fsub_rn(__fsub_rn(__fmul_rn(-0.5f, __fmul_rn(eb0, eb0)), logf(pb.z)), HLOG2PI);
  float lb1 = __fsub_rn(__fsub_rn(__fmul_rn(-0.5f, __fmul_rn(eb1, eb1)), logf(pb.w)), HLOG2PI);
  float lpa = __fadd_rn(la0, la1);
  float lpb = __fadd_rn(lb0, lb1);

  out[id] = sigmoid_(sigmoid_(__fsub_rn(lpa, lpb)));
}

// ---------------- Launch ----------------
extern "C" void kernel_launch(void* const* d_in, const int* in_sizes, int n_in,
                              void* d_out, int out_size, void* d_ws, size_t ws_size,
                              hipStream_t stream) {
  const float* post  = (const float*)d_in[0];
  const float* image = (const float*)d_in[1];
  const float* sim   = (const float*)d_in[2];
  const float* tW1 = (const float*)d_in[3];
  const float* tb1 = (const float*)d_in[4];
  const float* tW2 = (const float*)d_in[5];
  const float* tb2 = (const float*)d_in[6];
  const float* iW1 = (const float*)d_in[7];
  const float* ib1 = (const float*)d_in[8];
  const float* iW2 = (const float*)d_in[9];
  const float* ib2 = (const float*)d_in[10];
  float* out = (float*)d_out;

  int* idx_p = (int*)d_ws;
  int* idx_i = idx_p + MM;
  float4* params_t = (float4*)(idx_i + MM);       // GG float4s
  float4* params_i = params_t + GG;

  // jax.random.split(key(42)) under threefry_partitionable:
  // child i = full 64-bit PRF output at counter (hi=0, lo=i).
  uint32_t k1a = 0, k1b = 0; tf2x32(0u, 42u, k1a, k1b);   // child 0
  uint32_t k2a = 0, k2b = 1; tf2x32(0u, 42u, k2a, k2b);   // child 1

  argmax_kernel<<<dim3(2 * BB), dim3(256), 0, stream>>>(sim, idx_p, idx_i);
  mlp_kernel<<<dim3(2 * MBLK), dim3(256), 0, stream>>>(
      post, image, tW1, tb1, tW2, tb2, iW1, ib1, iW2, ib2, params_t, params_i);
  combine_kernel<<<dim3((2 * MM) / 256), dim3(256), 0, stream>>>(
      idx_p, idx_i, params_t, params_i, out, k1a, k1b, k2a, k2b);
}

// Round 13
// 105.292 us; speedup vs baseline: 1.6072x; 1.3923x over previous
//
#include <hip/hip_runtime.h>
#include <stdint.h>
#include <math.h>

// Problem constants
#define BB   1024
#define TT   197
#define SS   196
#define DD   64
#define MM   200704   // BB*SS   (outputs per side)
#define GG   201728   // BB*TT   (param rows per table)
#define MROWS 256     // rows per MLP block (64 per wave)
#define MBLK  788     // GG/MROWS blocks per side

using short8 = __attribute__((ext_vector_type(8))) short;   // 8 bf16 (A/B frag)
using f32x4  = __attribute__((ext_vector_type(4))) float;   // C/D frag

// ---------------- Threefry2x32 (exact JAX rolled variant) ----------------
static __host__ __device__ inline uint32_t rotl_(uint32_t x, int r) {
  return (x << r) | (x >> (32 - r));
}

static __host__ __device__ inline void tf2x32(uint32_t k0, uint32_t k1,
                                              uint32_t& x0, uint32_t& x1) {
  uint32_t ks2 = k0 ^ k1 ^ 0x1BD11BDAu;
  x0 += k0; x1 += k1;
  x0 += x1; x1 = rotl_(x1,13); x1 ^= x0;
  x0 += x1; x1 = rotl_(x1,15); x1 ^= x0;
  x0 += x1; x1 = rotl_(x1,26); x1 ^= x0;
  x0 += x1; x1 = rotl_(x1, 6); x1 ^= x0;
  x0 += k1;  x1 += ks2 + 1u;
  x0 += x1; x1 = rotl_(x1,17); x1 ^= x0;
  x0 += x1; x1 = rotl_(x1,29); x1 ^= x0;
  x0 += x1; x1 = rotl_(x1,16); x1 ^= x0;
  x0 += x1; x1 = rotl_(x1,24); x1 ^= x0;
  x0 += ks2; x1 += k0 + 2u;
  x0 += x1; x1 = rotl_(x1,13); x1 ^= x0;
  x0 += x1; x1 = rotl_(x1,15); x1 ^= x0;
  x0 += x1; x1 = rotl_(x1,26); x1 ^= x0;
  x0 += x1; x1 = rotl_(x1, 6); x1 ^= x0;
  x0 += k0;  x1 += k1 + 3u;
  x0 += x1; x1 = rotl_(x1,17); x1 ^= x0;
  x0 += x1; x1 = rotl_(x1,29); x1 ^= x0;
  x0 += x1; x1 = rotl_(x1,16); x1 ^= x0;
  x0 += x1; x1 = rotl_(x1,24); x1 ^= x0;
  x0 += k1;  x1 += ks2 + 4u;
  x0 += x1; x1 = rotl_(x1,13); x1 ^= x0;
  x0 += x1; x1 = rotl_(x1,15); x1 ^= x0;
  x0 += x1; x1 = rotl_(x1,26); x1 ^= x0;
  x0 += x1; x1 = rotl_(x1, 6); x1 ^= x0;
  x0 += ks2; x1 += k0 + 5u;
}

// XLA ErfInv (float32 Giles polynomial), exact non-contracted rounding.
static __device__ inline float erfinv_xla(float x) {
  float w = -log1pf(-__fmul_rn(x, x));
  float p;
  if (w < 5.0f) {
    w = __fsub_rn(w, 2.5f);
    p = 2.81022636e-08f;
    p = __fadd_rn(__fmul_rn(p, w), 3.43273939e-07f);
    p = __fadd_rn(__fmul_rn(p, w), -3.5233877e-06f);
    p = __fadd_rn(__fmul_rn(p, w), -4.39150654e-06f);
    p = __fadd_rn(__fmul_rn(p, w), 0.00021858087f);
    p = __fadd_rn(__fmul_rn(p, w), -0.00125372503f);
    p = __fadd_rn(__fmul_rn(p, w), -0.00417768164f);
    p = __fadd_rn(__fmul_rn(p, w), 0.246640727f);
    p = __fadd_rn(__fmul_rn(p, w), 1.50140941f);
  } else {
    w = __fsub_rn(sqrtf(w), 3.0f);
    p = -0.000200214257f;
    p = __fadd_rn(__fmul_rn(p, w), 0.000100950558f);
    p = __fadd_rn(__fmul_rn(p, w), 0.00134934322f);
    p = __fadd_rn(__fmul_rn(p, w), -0.00367342844f);
    p = __fadd_rn(__fmul_rn(p, w), 0.00573950773f);
    p = __fadd_rn(__fmul_rn(p, w), -0.0076224613f);
    p = __fadd_rn(__fmul_rn(p, w), 0.00943887047f);
    p = __fadd_rn(__fmul_rn(p, w), 1.00167406f);
    p = __fadd_rn(__fmul_rn(p, w), 2.83297682f);
  }
  return __fmul_rn(p, x);
}

// eps[e] of jax.random.normal under jax_threefry_partitionable=True:
// per-element counter PRF, counter (hi=0, lo=e), draw = x0out ^ x1out.
static __device__ inline float jax_normal_elem(uint32_t k0, uint32_t k1, uint32_t e) {
  uint32_t c0 = 0u, c1 = e;
  tf2x32(k0, k1, c0, c1);
  uint32_t bits = c0 ^ c1;
  float f = __fsub_rn(__uint_as_float((bits >> 9) | 0x3F800000u), 1.0f); // [0,1)
  const float lo = -0.99999994f;
  float u = fmaxf(lo, __fadd_rn(__fmul_rn(f, 2.0f), lo));
  return __fmul_rn(1.41421356237309515f, erfinv_xla(u));
}

static __device__ inline float softplus_(float x) {
  return __fadd_rn(fmaxf(x, 0.0f), log1pf(expf(-fabsf(x))));
}

static __device__ inline float sigmoid_(float x) {
  if (x >= 0.0f) return 1.0f / (1.0f + expf(-x));
  float e = expf(x);
  return e / (1.0f + e);
}

// exact 3-way truncation split of fp32 -> 3 bf16 terms (b1+b2+b3 == x exactly
// for normal-range x: 8+8+8 mantissa bits cover fp32's 24)
static __device__ inline void split1(float x, uint32_t& h1, uint32_t& h2, uint32_t& h3) {
  uint32_t xb = __float_as_uint(x);
  h1 = xb & 0xFFFF0000u;
  float r1 = __fsub_rn(x, __uint_as_float(h1));   // exact
  uint32_t rb = __float_as_uint(r1);
  h2 = rb & 0xFFFF0000u;
  float r2 = __fsub_rn(r1, __uint_as_float(h2));  // exact, fits 8 mantissa bits
  h3 = __float_as_uint(r2);                       // low 16 bits are zero
}

static __device__ inline void split8(f32x4 lo, f32x4 hi,
                                     short8& s1, short8& s2, short8& s3) {
  #pragma unroll
  for (int j = 0; j < 8; ++j) {
    float x = (j < 4) ? lo[j] : hi[j - 4];
    uint32_t h1, h2, h3;
    split1(x, h1, h2, h3);
    s1[j] = (short)(h1 >> 16);
    s2[j] = (short)(h2 >> 16);
    s3[j] = (short)(h3 >> 16);
  }
}

// ---------------- Kernel 1: argmax, shuffle-free, phase-split blocks ----------------
// (unchanged since R5)
__global__ __launch_bounds__(256) void argmax_kernel(
    const float* __restrict__ sim, int* __restrict__ idx_p, int* __restrict__ idx_i) {
  int bid = blockIdx.x;
  int b = bid >> 1, phase = bid & 1;
  int j = threadIdx.x;
  if (j >= SS) return;
  const float* S = sim + (size_t)b * (TT * TT);

  if (phase == 0) {
    const float* p = S + TT + 1 + j;   // S[1][1+j]
    float v0 = -INFINITY, v1 = -INFINITY, v2 = -INFINITY, v3 = -INFINITY;
    int t0 = 0, t1 = 1, t2 = 2, t3 = 3;
    for (int t = 0; t < SS; t += 4) {
      float a  = p[(size_t)(t + 0) * TT];
      float c1 = p[(size_t)(t + 1) * TT];
      float c2 = p[(size_t)(t + 2) * TT];
      float c3 = p[(size_t)(t + 3) * TT];
      if (a  > v0) { v0 = a;  t0 = t; }
      if (c1 > v1) { v1 = c1; t1 = t + 1; }
      if (c2 > v2) { v2 = c2; t2 = t + 2; }
      if (c3 > v3) { v3 = c3; t3 = t + 3; }
    }
    float bv = v0; int bt = t0;
    if (v1 > bv || (v1 == bv && t1 < bt)) { bv = v1; bt = t1; }
    if (v2 > bv || (v2 == bv && t2 < bt)) { bv = v2; bt = t2; }
    if (v3 > bv || (v3 == bv && t3 < bt)) { bv = v3; bt = t3; }
    idx_i[(size_t)b * SS + j] = bt;
  } else {
    const float* q = S + (size_t)(j + 1) * TT + 1;   // S[1+j][1]
    float v[4] = {-INFINITY, -INFINITY, -INFINITY, -INFINITY};
    int   ci[4] = {0, 1, 2, 3};
    for (int c = 0; c < 192; c += 16) {
      #pragma unroll
      for (int u = 0; u < 16; ++u) {
        float x = q[c + u];
        int k = u & 3;
        if (x > v[k]) { v[k] = x; ci[k] = c + u; }
      }
    }
    #pragma unroll
    for (int u = 0; u < 4; ++u) {
      float x = q[192 + u];
      if (x > v[u]) { v[u] = x; ci[u] = 192 + u; }
    }
    float bv = v[0]; int bc = ci[0];
    #pragma unroll
    for (int k = 1; k < 4; ++k)
      if (v[k] > bv || (v[k] == bv && ci[k] < bc)) { bv = v[k]; bc = ci[k]; }
    idx_p[(size_t)b * SS + j] = bc;
  }
}

// ---------------- Kernel 2: MFMA MLP (exact 3-split bf16, 6 passes) ----------------
// Computes Y^T = W1^T . X^T via mfma_f32_16x16x32_bf16 so that C/D's
// col=lane&15 indexes the X-row: A = W1^T tile (M=W1 cols), B = X^T (N=rows).
// X streams directly from global into B-frags (no X LDS). W1 is split+
// transposed into LDS bf16 once per block (stride 72 to avoid bank conflicts).
// Layer 2 (64x4) per-lane partials + 2-step shfl_xor reduce.
__global__ __launch_bounds__(256) void mlp_kernel(
    const float* __restrict__ Xp, const float* __restrict__ Xi,
    const float* __restrict__ tW1, const float* __restrict__ tb1,
    const float* __restrict__ tW2, const float* __restrict__ tb2,
    const float* __restrict__ iW1, const float* __restrict__ ib1,
    const float* __restrict__ iW2, const float* __restrict__ ib2,
    float4* __restrict__ params_t, float4* __restrict__ params_i) {
  __shared__ short  W1T3[3][64][72];   // [split][col][k] bf16, 27.6 KB
  __shared__ float4 W2s[64];
  __shared__ float  b1s[64];
  __shared__ float  b2s[4];

  int tid = threadIdx.x;
  int bid = blockIdx.x;
  int side = (bid >= MBLK) ? 1 : 0;
  const float* X  = side ? Xi  : Xp;
  const float* W1 = side ? iW1 : tW1;
  const float* B1 = side ? ib1 : tb1;
  const float* W2 = side ? iW2 : tW2;
  const float* B2 = side ? ib2 : tb2;
  float4* params  = side ? params_i : params_t;
  size_t g0 = (size_t)(side ? bid - MBLK : bid) * MROWS;

  // ---- stage W1^T split into LDS: thread (col = tid&63, kc = tid>>6) ----
  {
    int col = tid & 63, kc = tid >> 6;           // kc in 0..3, k-range kc*16..+15
    uint32_t wv[3][8];
    #pragma unroll
    for (int kk = 0; kk < 16; kk += 2) {
      float xe = W1[(size_t)(kc * 16 + kk) * 64 + col];
      float xo = W1[(size_t)(kc * 16 + kk + 1) * 64 + col];
      uint32_t e1, e2, e3, o1, o2, o3;
      split1(xe, e1, e2, e3);
      split1(xo, o1, o2, o3);
      wv[0][kk >> 1] = (e1 >> 16) | o1;          // lo = even k, hi = odd k
      wv[1][kk >> 1] = (e2 >> 16) | o2;
      wv[2][kk >> 1] = (e3 >> 16) | o3;
    }
    #pragma unroll
    for (int s = 0; s < 3; ++s) {
      uint32_t* dst = (uint32_t*)&W1T3[s][col][kc * 16];
      #pragma unroll
      for (int q = 0; q < 8; ++q) dst[q] = wv[s][q];
    }
  }
  if (tid < 64) {
    W2s[tid] = ((const float4*)W2)[tid];
    b1s[tid] = B1[tid];
  }
  if (tid < 4) b2s[tid] = B2[tid];
  __syncthreads();

  int w = tid >> 6, lane = tid & 63;
  int ln = lane & 15, hi = lane >> 4;
  int hi8 = hi * 8, hi4 = hi * 4;

  // hold all A-frags (W1^T): lane holds A[m=ln][k=hi8+j] per (split, mt, ks)
  short8 Aw[3][4][2];
  #pragma unroll
  for (int s = 0; s < 3; ++s)
    #pragma unroll
    for (int mt = 0; mt < 4; ++mt)
      #pragma unroll
      for (int ks = 0; ks < 2; ++ks)
        Aw[s][mt][ks] = *(const short8*)&W1T3[s][mt * 16 + ln][ks * 32 + hi8];

  f32x4 b1v[4];
  #pragma unroll
  for (int mt = 0; mt < 4; ++mt)
    b1v[mt] = *(const f32x4*)&b1s[mt * 16 + hi4];

  size_t rowbase = g0 + (size_t)w * 64;
  // pass order: small terms first. (a=W1-split, b=X-split), levels 0-indexed.
  const int PA[6] = {2, 0, 1, 1, 0, 0};
  const int PB[6] = {0, 2, 1, 0, 1, 0};

  #pragma unroll 1
  for (int nt = 0; nt < 4; ++nt) {
    const float* xrow = X + (rowbase + nt * 16 + ln) * 64;
    f32x4 xa0 = *(const f32x4*)(xrow + hi8);
    f32x4 xa1 = *(const f32x4*)(xrow + hi8 + 4);
    f32x4 xb0 = *(const f32x4*)(xrow + 32 + hi8);
    f32x4 xb1 = *(const f32x4*)(xrow + 32 + hi8 + 4);

    short8 Bx[3][2];
    split8(xa0, xa1, Bx[0][0], Bx[1][0], Bx[2][0]);
    split8(xb0, xb1, Bx[0][1], Bx[1][1], Bx[2][1]);

    f32x4 accv[4];
    #pragma unroll
    for (int mt = 0; mt < 4; ++mt) accv[mt] = (f32x4){0.f, 0.f, 0.f, 0.f};

    #pragma unroll
    for (int p = 0; p < 6; ++p)
      #pragma unroll
      for (int mt = 0; mt < 4; ++mt)
        #pragma unroll
        for (int ks = 0; ks < 2; ++ks)
          accv[mt] = __builtin_amdgcn_mfma_f32_16x16x32_bf16(
              Aw[PA[p]][mt][ks], Bx[PB[p]][ks], accv[mt], 0, 0, 0);

    // epilogue: lane holds Y[row = rowbase+nt*16+ln][col = mt*16+hi4+v]
    float p0 = 0.f, p1 = 0.f, p2 = 0.f, p3 = 0.f;
    #pragma unroll
    for (int mt = 0; mt < 4; ++mt)
      #pragma unroll
      for (int v = 0; v < 4; ++v) {
        float y = accv[mt][v] + b1v[mt][v];
        y = fmaxf(y, 0.0f);
        float4 w2 = W2s[mt * 16 + hi4 + v];
        p0 = fmaf(y, w2.x, p0);
        p1 = fmaf(y, w2.y, p1);
        p2 = fmaf(y, w2.z, p2);
        p3 = fmaf(y, w2.w, p3);
      }
    // reduce across the 4 lane-groups (each holds 16 of the 64 cols)
    p0 += __shfl_xor(p0, 16); p0 += __shfl_xor(p0, 32);
    p1 += __shfl_xor(p1, 16); p1 += __shfl_xor(p1, 32);
    p2 += __shfl_xor(p2, 16); p2 += __shfl_xor(p2, 32);
    p3 += __shfl_xor(p3, 16); p3 += __shfl_xor(p3, 32);

    if (lane < 16) {
      float m0 = p0 + b2s[0];
      float m1 = p1 + b2s[1];
      float s0 = __fadd_rn(softplus_(p2 + b2s[2]), 1e-07f);
      float s1 = __fadd_rn(softplus_(p3 + b2s[3]), 1e-07f);
      params[rowbase + nt * 16 + lane] = make_float4(m0, m1, s0, s1);
    }
  }
}

// ---------------- Kernel 3: gather params, sample eps, log-prob diff ----------------
__global__ __launch_bounds__(256) void combine_kernel(
    const int* __restrict__ idx_p, const int* __restrict__ idx_i,
    const float4* __restrict__ params_t, const float4* __restrict__ params_i,
    float* __restrict__ out,
    uint32_t k1a, uint32_t k1b, uint32_t k2a, uint32_t k2b) {
  int id = blockIdx.x * 256 + threadIdx.x;
  int side = (id >= MM) ? 1 : 0;             // wave-uniform (MM % 256 == 0)
  int m = id - side * MM;
  int b = m / SS;
  int t = m - b * SS;

  float4 pa, pb;
  uint32_t ka, kb;
  if (!side) {
    pa = params_t[(size_t)b * TT + 1 + t];
    pb = params_i[(size_t)b * TT + idx_p[m]];
    ka = k1a; kb = k1b;
  } else {
    pa = params_i[(size_t)b * TT + 1 + t];
    pb = params_t[(size_t)b * TT + idx_i[m]];
    ka = k2a; kb = k2b;
  }

  uint32_t e0 = 2u * (uint32_t)m;
  float eps0 = jax_normal_elem(ka, kb, e0);
  float eps1 = jax_normal_elem(ka, kb, e0 + 1u);

  float z0 = __fadd_rn(pa.x, __fmul_rn(pa.z, eps0));
  float z1 = __fadd_rn(pa.y, __fmul_rn(pa.w, eps1));

  const float HLOG2PI = 0.91893853320467274f;
  float ea0 = __fsub_rn(z0, pa.x) / pa.z;
  float ea1 = __fsub_rn(z1, pa.y) / pa.w;
  float eb0 = __fsub_rn(z0, pb.x) / pb.z;
  float eb1 = __fsub_rn(z1, pb.y) / pb.w;

  float la0 = __fsub_rn(__fsub_rn(__fmul_rn(-0.5f, __fmul_rn(ea0, ea0)), logf(pa.z)), HLOG2PI);
  float la1 = __fsub_rn(__fsub_rn(__fmul_rn(-0.5f, __fmul_rn(ea1, ea1)), logf(pa.w)), HLOG2PI);
  float lb0 = __fsub_rn(__fsub_rn(__fmul_rn(-0.5f, __fmul_rn(eb0, eb0)), logf(pb.z)), HLOG2PI);
  float lb1 = __fsub_rn(__fsub_rn(__fmul_rn(-0.5f, __fmul_rn(eb1, eb1)), logf(pb.w)), HLOG2PI);
  float lpa = __fadd_rn(la0, la1);
  float lpb = __fadd_rn(lb0, lb1);

  out[id] = sigmoid_(sigmoid_(__fsub_rn(lpa, lpb)));
}

// ---------------- Launch ----------------
extern "C" void kernel_launch(void* const* d_in, const int* in_sizes, int n_in,
                              void* d_out, int out_size, void* d_ws, size_t ws_size,
                              hipStream_t stream) {
  const float* post  = (const float*)d_in[0];
  const float* image = (const float*)d_in[1];
  const float* sim   = (const float*)d_in[2];
  const float* tW1 = (const float*)d_in[3];
  const float* tb1 = (const float*)d_in[4];
  const float* tW2 = (const float*)d_in[5];
  const float* tb2 = (const float*)d_in[6];
  const float* iW1 = (const float*)d_in[7];
  const float* ib1 = (const float*)d_in[8];
  const float* iW2 = (const float*)d_in[9];
  const float* ib2 = (const float*)d_in[10];
  float* out = (float*)d_out;

  int* idx_p = (int*)d_ws;
  int* idx_i = idx_p + MM;
  float4* params_t = (float4*)(idx_i + MM);       // GG float4s
  float4* params_i = params_t + GG;

  // jax.random.split(key(42)) under threefry_partitionable:
  // child i = full 64-bit PRF output at counter (hi=0, lo=i).
  uint32_t k1a = 0, k1b = 0; tf2x32(0u, 42u, k1a, k1b);   // child 0
  uint32_t k2a = 0, k2b = 1; tf2x32(0u, 42u, k2a, k2b);   // child 1

  argmax_kernel<<<dim3(2 * BB), dim3(256), 0, stream>>>(sim, idx_p, idx_i);
  mlp_kernel<<<dim3(2 * MBLK), dim3(256), 0, stream>>>(
      post, image, tW1, tb1, tW2, tb2, iW1, ib1, iW2, ib2, params_t, params_i);
  combine_kernel<<<dim3((2 * MM) / 256), dim3(256), 0, stream>>>(
      idx_p, idx_i, params_t, params_i, out, k1a, k1b, k2a, k2b);
}

// Round 14
// 86.554 us; speedup vs baseline: 1.9551x; 1.2165x over previous
//
#include <hip/hip_runtime.h>
#include <stdint.h>
#include <math.h>

// Problem constants
#define BB   1024
#define TT   197
#define SS   196
#define DD   64
#define MM   200704   // BB*SS   (outputs per side)
#define GG   201728   // BB*TT   (param rows per table)
#define MROWS 256     // rows per MLP block (64 per wave)
#define MBLK  788     // GG/MROWS blocks per side
#define STRIP 49      // argmax strip rows (4 strips x 49 = 196)

using short8 = __attribute__((ext_vector_type(8))) short;   // 8 bf16 (A/B frag)
using f32x4  = __attribute__((ext_vector_type(4))) float;   // C/D frag

// ---------------- Threefry2x32 (exact JAX rolled variant) ----------------
static __host__ __device__ inline uint32_t rotl_(uint32_t x, int r) {
  return (x << r) | (x >> (32 - r));
}

static __host__ __device__ inline void tf2x32(uint32_t k0, uint32_t k1,
                                              uint32_t& x0, uint32_t& x1) {
  uint32_t ks2 = k0 ^ k1 ^ 0x1BD11BDAu;
  x0 += k0; x1 += k1;
  x0 += x1; x1 = rotl_(x1,13); x1 ^= x0;
  x0 += x1; x1 = rotl_(x1,15); x1 ^= x0;
  x0 += x1; x1 = rotl_(x1,26); x1 ^= x0;
  x0 += x1; x1 = rotl_(x1, 6); x1 ^= x0;
  x0 += k1;  x1 += ks2 + 1u;
  x0 += x1; x1 = rotl_(x1,17); x1 ^= x0;
  x0 += x1; x1 = rotl_(x1,29); x1 ^= x0;
  x0 += x1; x1 = rotl_(x1,16); x1 ^= x0;
  x0 += x1; x1 = rotl_(x1,24); x1 ^= x0;
  x0 += ks2; x1 += k0 + 2u;
  x0 += x1; x1 = rotl_(x1,13); x1 ^= x0;
  x0 += x1; x1 = rotl_(x1,15); x1 ^= x0;
  x0 += x1; x1 = rotl_(x1,26); x1 ^= x0;
  x0 += x1; x1 = rotl_(x1, 6); x1 ^= x0;
  x0 += k0;  x1 += k1 + 3u;
  x0 += x1; x1 = rotl_(x1,17); x1 ^= x0;
  x0 += x1; x1 = rotl_(x1,29); x1 ^= x0;
  x0 += x1; x1 = rotl_(x1,16); x1 ^= x0;
  x0 += x1; x1 = rotl_(x1,24); x1 ^= x0;
  x0 += k1;  x1 += ks2 + 4u;
  x0 += x1; x1 = rotl_(x1,13); x1 ^= x0;
  x0 += x1; x1 = rotl_(x1,15); x1 ^= x0;
  x0 += x1; x1 = rotl_(x1,26); x1 ^= x0;
  x0 += x1; x1 = rotl_(x1, 6); x1 ^= x0;
  x0 += ks2; x1 += k0 + 5u;
}

// XLA ErfInv (float32 Giles polynomial), exact non-contracted rounding.
static __device__ inline float erfinv_xla(float x) {
  float w = -log1pf(-__fmul_rn(x, x));
  float p;
  if (w < 5.0f) {
    w = __fsub_rn(w, 2.5f);
    p = 2.81022636e-08f;
    p = __fadd_rn(__fmul_rn(p, w), 3.43273939e-07f);
    p = __fadd_rn(__fmul_rn(p, w), -3.5233877e-06f);
    p = __fadd_rn(__fmul_rn(p, w), -4.39150654e-06f);
    p = __fadd_rn(__fmul_rn(p, w), 0.00021858087f);
    p = __fadd_rn(__fmul_rn(p, w), -0.00125372503f);
    p = __fadd_rn(__fmul_rn(p, w), -0.00417768164f);
    p = __fadd_rn(__fmul_rn(p, w), 0.246640727f);
    p = __fadd_rn(__fmul_rn(p, w), 1.50140941f);
  } else {
    w = __fsub_rn(sqrtf(w), 3.0f);
    p = -0.000200214257f;
    p = __fadd_rn(__fmul_rn(p, w), 0.000100950558f);
    p = __fadd_rn(__fmul_rn(p, w), 0.00134934322f);
    p = __fadd_rn(__fmul_rn(p, w), -0.00367342844f);
    p = __fadd_rn(__fmul_rn(p, w), 0.00573950773f);
    p = __fadd_rn(__fmul_rn(p, w), -0.0076224613f);
    p = __fadd_rn(__fmul_rn(p, w), 0.00943887047f);
    p = __fadd_rn(__fmul_rn(p, w), 1.00167406f);
    p = __fadd_rn(__fmul_rn(p, w), 2.83297682f);
  }
  return __fmul_rn(p, x);
}

// eps[e] of jax.random.normal under jax_threefry_partitionable=True:
// per-element counter PRF, counter (hi=0, lo=e), draw = x0out ^ x1out.
static __device__ inline float jax_normal_elem(uint32_t k0, uint32_t k1, uint32_t e) {
  uint32_t c0 = 0u, c1 = e;
  tf2x32(k0, k1, c0, c1);
  uint32_t bits = c0 ^ c1;
  float f = __fsub_rn(__uint_as_float((bits >> 9) | 0x3F800000u), 1.0f); // [0,1)
  const float lo = -0.99999994f;
  float u = fmaxf(lo, __fadd_rn(__fmul_rn(f, 2.0f), lo));
  return __fmul_rn(1.41421356237309515f, erfinv_xla(u));
}

static __device__ inline float softplus_(float x) {
  return __fadd_rn(fmaxf(x, 0.0f), log1pf(expf(-fabsf(x))));
}

static __device__ inline float sigmoid_(float x) {
  if (x >= 0.0f) return 1.0f / (1.0f + expf(-x));
  float e = expf(x);
  return e / (1.0f + e);
}

// exact 3-way truncation split of fp32 -> 3 bf16 terms
static __device__ inline void split1(float x, uint32_t& h1, uint32_t& h2, uint32_t& h3) {
  uint32_t xb = __float_as_uint(x);
  h1 = xb & 0xFFFF0000u;
  float r1 = __fsub_rn(x, __uint_as_float(h1));   // exact
  uint32_t rb = __float_as_uint(r1);
  h2 = rb & 0xFFFF0000u;
  float r2 = __fsub_rn(r1, __uint_as_float(h2));  // exact, fits 8 mantissa bits
  h3 = __float_as_uint(r2);                       // low 16 bits are zero
}

static __device__ inline void split8(f32x4 lo, f32x4 hi,
                                     short8& s1, short8& s2, short8& s3) {
  #pragma unroll
  for (int j = 0; j < 8; ++j) {
    float x = (j < 4) ? lo[j] : hi[j - 4];
    uint32_t h1, h2, h3;
    split1(x, h1, h2, h3);
    s1[j] = (short)(h1 >> 16);
    s2[j] = (short)(h2 >> 16);
    s3[j] = (short)(h3 >> 16);
  }
}

// ---------------- Kernel 1: single-pass argmax (row + col in one read) ----------------
// One block per batch. 4 strips of 49 rows: threads j<196 stream strip rows
// coalesced (running col-max in register -> idx_i), staging into LDS; then 245
// threads compute row-argmax partials (5 parts x 40 cols) and 49 combine.
__global__ __launch_bounds__(256) void argmax_kernel(
    const float* __restrict__ sim, int* __restrict__ idx_p, int* __restrict__ idx_i) {
  __shared__ float tile[STRIP][197];   // pad 197: bank stride 5 (coprime 32)
  __shared__ float pv[STRIP][5];
  __shared__ int   pi[STRIP][5];

  int b = blockIdx.x;
  int tid = threadIdx.x;
  const float* S = sim + (size_t)b * (TT * TT);

  float cv = -INFINITY; int ct = 0;          // column running max (thread = col j)
  int r5 = tid / 5, p5 = tid - r5 * 5;       // row-scan role (tid < 245)
  int cbeg = p5 * 40;
  int cend = (p5 == 4) ? 196 : (cbeg + 40);

  #pragma unroll 1
  for (int s = 0; s < 4; ++s) {
    // ---- load strip rows s*49 .. s*49+48, coalesced across j ----
    if (tid < SS) {
      const float* base = S + (size_t)(1 + s * STRIP) * TT + 1 + tid;
      #pragma unroll 7
      for (int tt = 0; tt < STRIP; ++tt) {
        float x = base[(size_t)tt * TT];
        tile[tt][tid] = x;
        if (x > cv) { cv = x; ct = s * STRIP + tt; }   // ascending t, strict >
      }
    }
    __syncthreads();

    // ---- row-argmax partials: thread (r5, p5) scans cols [cbeg, cend) ----
    if (tid < 245) {
      float bv = -INFINITY; int bc = cbeg;
      for (int c = cbeg; c < cend; ++c) {
        float x = tile[r5][c];
        if (x > bv) { bv = x; bc = c; }      // ascending c, strict >
      }
      pv[r5][p5] = bv; pi[r5][p5] = bc;
    }
    __syncthreads();

    // ---- combine 5 parts (ascending part => ascending c; strict > keeps first) ----
    if (tid < STRIP) {
      float bv = pv[tid][0]; int bc = pi[tid][0];
      #pragma unroll
      for (int p = 1; p < 5; ++p) {
        float v = pv[tid][p];
        if (v > bv) { bv = v; bc = pi[tid][p]; }
      }
      idx_p[(size_t)b * SS + s * STRIP + tid] = bc;
    }
    __syncthreads();   // tile consumed; safe to overwrite next strip
  }

  if (tid < SS) idx_i[(size_t)b * SS + tid] = ct;
}

// ---------------- Kernel 2: MFMA MLP (exact 3-split bf16, 6 passes) ----------------
// (byte-identical to R13)
__global__ __launch_bounds__(256) void mlp_kernel(
    const float* __restrict__ Xp, const float* __restrict__ Xi,
    const float* __restrict__ tW1, const float* __restrict__ tb1,
    const float* __restrict__ tW2, const float* __restrict__ tb2,
    const float* __restrict__ iW1, const float* __restrict__ ib1,
    const float* __restrict__ iW2, const float* __restrict__ ib2,
    float4* __restrict__ params_t, float4* __restrict__ params_i) {
  __shared__ short  W1T3[3][64][72];   // [split][col][k] bf16, 27.6 KB
  __shared__ float4 W2s[64];
  __shared__ float  b1s[64];
  __shared__ float  b2s[4];

  int tid = threadIdx.x;
  int bid = blockIdx.x;
  int side = (bid >= MBLK) ? 1 : 0;
  const float* X  = side ? Xi  : Xp;
  const float* W1 = side ? iW1 : tW1;
  const float* B1 = side ? ib1 : tb1;
  const float* W2 = side ? iW2 : tW2;
  const float* B2 = side ? ib2 : tb2;
  float4* params  = side ? params_i : params_t;
  size_t g0 = (size_t)(side ? bid - MBLK : bid) * MROWS;

  // ---- stage W1^T split into LDS: thread (col = tid&63, kc = tid>>6) ----
  {
    int col = tid & 63, kc = tid >> 6;
    uint32_t wv[3][8];
    #pragma unroll
    for (int kk = 0; kk < 16; kk += 2) {
      float xe = W1[(size_t)(kc * 16 + kk) * 64 + col];
      float xo = W1[(size_t)(kc * 16 + kk + 1) * 64 + col];
      uint32_t e1, e2, e3, o1, o2, o3;
      split1(xe, e1, e2, e3);
      split1(xo, o1, o2, o3);
      wv[0][kk >> 1] = (e1 >> 16) | o1;
      wv[1][kk >> 1] = (e2 >> 16) | o2;
      wv[2][kk >> 1] = (e3 >> 16) | o3;
    }
    #pragma unroll
    for (int s = 0; s < 3; ++s) {
      uint32_t* dst = (uint32_t*)&W1T3[s][col][kc * 16];
      #pragma unroll
      for (int q = 0; q < 8; ++q) dst[q] = wv[s][q];
    }
  }
  if (tid < 64) {
    W2s[tid] = ((const float4*)W2)[tid];
    b1s[tid] = B1[tid];
  }
  if (tid < 4) b2s[tid] = B2[tid];
  __syncthreads();

  int w = tid >> 6, lane = tid & 63;
  int ln = lane & 15, hi = lane >> 4;
  int hi8 = hi * 8, hi4 = hi * 4;

  short8 Aw[3][4][2];
  #pragma unroll
  for (int s = 0; s < 3; ++s)
    #pragma unroll
    for (int mt = 0; mt < 4; ++mt)
      #pragma unroll
      for (int ks = 0; ks < 2; ++ks)
        Aw[s][mt][ks] = *(const short8*)&W1T3[s][mt * 16 + ln][ks * 32 + hi8];

  f32x4 b1v[4];
  #pragma unroll
  for (int mt = 0; mt < 4; ++mt)
    b1v[mt] = *(const f32x4*)&b1s[mt * 16 + hi4];

  size_t rowbase = g0 + (size_t)w * 64;
  const int PA[6] = {2, 0, 1, 1, 0, 0};
  const int PB[6] = {0, 2, 1, 0, 1, 0};

  #pragma unroll 1
  for (int nt = 0; nt < 4; ++nt) {
    const float* xrow = X + (rowbase + nt * 16 + ln) * 64;
    f32x4 xa0 = *(const f32x4*)(xrow + hi8);
    f32x4 xa1 = *(const f32x4*)(xrow + hi8 + 4);
    f32x4 xb0 = *(const f32x4*)(xrow + 32 + hi8);
    f32x4 xb1 = *(const f32x4*)(xrow + 32 + hi8 + 4);

    short8 Bx[3][2];
    split8(xa0, xa1, Bx[0][0], Bx[1][0], Bx[2][0]);
    split8(xb0, xb1, Bx[0][1], Bx[1][1], Bx[2][1]);

    f32x4 accv[4];
    #pragma unroll
    for (int mt = 0; mt < 4; ++mt) accv[mt] = (f32x4){0.f, 0.f, 0.f, 0.f};

    #pragma unroll
    for (int p = 0; p < 6; ++p)
      #pragma unroll
      for (int mt = 0; mt < 4; ++mt)
        #pragma unroll
        for (int ks = 0; ks < 2; ++ks)
          accv[mt] = __builtin_amdgcn_mfma_f32_16x16x32_bf16(
              Aw[PA[p]][mt][ks], Bx[PB[p]][ks], accv[mt], 0, 0, 0);

    float p0 = 0.f, p1 = 0.f, p2 = 0.f, p3 = 0.f;
    #pragma unroll
    for (int mt = 0; mt < 4; ++mt)
      #pragma unroll
      for (int v = 0; v < 4; ++v) {
        float y = accv[mt][v] + b1v[mt][v];
        y = fmaxf(y, 0.0f);
        float4 w2 = W2s[mt * 16 + hi4 + v];
        p0 = fmaf(y, w2.x, p0);
        p1 = fmaf(y, w2.y, p1);
        p2 = fmaf(y, w2.z, p2);
        p3 = fmaf(y, w2.w, p3);
      }
    p0 += __shfl_xor(p0, 16); p0 += __shfl_xor(p0, 32);
    p1 += __shfl_xor(p1, 16); p1 += __shfl_xor(p1, 32);
    p2 += __shfl_xor(p2, 16); p2 += __shfl_xor(p2, 32);
    p3 += __shfl_xor(p3, 16); p3 += __shfl_xor(p3, 32);

    if (lane < 16) {
      float m0 = p0 + b2s[0];
      float m1 = p1 + b2s[1];
      float s0 = __fadd_rn(softplus_(p2 + b2s[2]), 1e-07f);
      float s1 = __fadd_rn(softplus_(p3 + b2s[3]), 1e-07f);
      params[rowbase + nt * 16 + lane] = make_float4(m0, m1, s0, s1);
    }
  }
}

// ---------------- Kernel 3: gather params, sample eps, log-prob diff ----------------
__global__ __launch_bounds__(256) void combine_kernel(
    const int* __restrict__ idx_p, const int* __restrict__ idx_i,
    const float4* __restrict__ params_t, const float4* __restrict__ params_i,
    float* __restrict__ out,
    uint32_t k1a, uint32_t k1b, uint32_t k2a, uint32_t k2b) {
  int id = blockIdx.x * 256 + threadIdx.x;
  int side = (id >= MM) ? 1 : 0;             // wave-uniform (MM % 256 == 0)
  int m = id - side * MM;
  int b = m / SS;
  int t = m - b * SS;

  float4 pa, pb;
  uint32_t ka, kb;
  if (!side) {
    pa = params_t[(size_t)b * TT + 1 + t];
    pb = params_i[(size_t)b * TT + idx_p[m]];
    ka = k1a; kb = k1b;
  } else {
    pa = params_i[(size_t)b * TT + 1 + t];
    pb = params_t[(size_t)b * TT + idx_i[m]];
    ka = k2a; kb = k2b;
  }

  uint32_t e0 = 2u * (uint32_t)m;
  float eps0 = jax_normal_elem(ka, kb, e0);
  float eps1 = jax_normal_elem(ka, kb, e0 + 1u);

  float z0 = __fadd_rn(pa.x, __fmul_rn(pa.z, eps0));
  float z1 = __fadd_rn(pa.y, __fmul_rn(pa.w, eps1));

  const float HLOG2PI = 0.91893853320467274f;
  float ea0 = __fsub_rn(z0, pa.x) / pa.z;
  float ea1 = __fsub_rn(z1, pa.y) / pa.w;
  float eb0 = __fsub_rn(z0, pb.x) / pb.z;
  float eb1 = __fsub_rn(z1, pb.y) / pb.w;

  float la0 = __fsub_rn(__fsub_rn(__fmul_rn(-0.5f, __fmul_rn(ea0, ea0)), logf(pa.z)), HLOG2PI);
  float la1 = __fsub_rn(__fsub_rn(__fmul_rn(-0.5f, __fmul_rn(ea1, ea1)), logf(pa.w)), HLOG2PI);
  float lb0 = __fsub_rn(__fsub_rn(__fmul_rn(-0.5f, __fmul_rn(eb0, eb0)), logf(pb.z)), HLOG2PI);
  float lb1 = __fsub_rn(__fsub_rn(__fmul_rn(-0.5f, __fmul_rn(eb1, eb1)), logf(pb.w)), HLOG2PI);
  float lpa = __fadd_rn(la0, la1);
  float lpb = __fadd_rn(lb0, lb1);

  out[id] = sigmoid_(sigmoid_(__fsub_rn(lpa, lpb)));
}

// ---------------- Launch ----------------
extern "C" void kernel_launch(void* const* d_in, const int* in_sizes, int n_in,
                              void* d_out, int out_size, void* d_ws, size_t ws_size,
                              hipStream_t stream) {
  const float* post  = (const float*)d_in[0];
  const float* image = (const float*)d_in[1];
  const float* sim   = (const float*)d_in[2];
  const float* tW1 = (const float*)d_in[3];
  const float* tb1 = (const float*)d_in[4];
  const float* tW2 = (const float*)d_in[5];
  const float* tb2 = (const float*)d_in[6];
  const float* iW1 = (const float*)d_in[7];
  const float* ib1 = (const float*)d_in[8];
  const float* iW2 = (const float*)d_in[9];
  const float* ib2 = (const float*)d_in[10];
  float* out = (float*)d_out;

  int* idx_p = (int*)d_ws;
  int* idx_i = idx_p + MM;
  float4* params_t = (float4*)(idx_i + MM);       // GG float4s
  float4* params_i = params_t + GG;

  // jax.random.split(key(42)) under threefry_partitionable:
  // child i = full 64-bit PRF output at counter (hi=0, lo=i).
  uint32_t k1a = 0, k1b = 0; tf2x32(0u, 42u, k1a, k1b);   // child 0
  uint32_t k2a = 0, k2b = 1; tf2x32(0u, 42u, k2a, k2b);   // child 1

  argmax_kernel<<<dim3(BB), dim3(256), 0, stream>>>(sim, idx_p, idx_i);
  mlp_kernel<<<dim3(2 * MBLK), dim3(256), 0, stream>>>(
      post, image, tW1, tb1, tW2, tb2, iW1, ib1, iW2, ib2, params_t, params_i);
  combine_kernel<<<dim3((2 * MM) / 256), dim3(256), 0, stream>>>(
      idx_p, idx_i, params_t, params_i, out, k1a, k1b, k2a, k2b);
}